// Round 17
// baseline (805.156 us; speedup 1.0000x reference)
//
#include <hip/hip_runtime.h>
#include <hip/hip_fp16.h>

#define N_NODES 100000
#define N_EDGES 1600000
#define TILE 2048
#define NBUK 64
#define BSH 11            // bucket = dst >> 11 (2048 nodes/bucket, 49 used)
#define NBUK_USED ((N_NODES + (1 << BSH) - 1) >> BSH)   // 49
#define CAP 36864         // fixed ebuf region per bucket
#define SMASK 0x1FFFF     // node-id guard mask (identity for id < 131072)
#define PRE_BLOCKS 12500
#define BINA_BLOCKS ((N_EDGES + TILE - 1) / TILE)       // 782

typedef _Float16 f16x8 __attribute__((ext_vector_type(8)));
typedef float    f32x4 __attribute__((ext_vector_type(4)));

// ---------------------------------------------------------------------------
// k_preA: grid-split merge of (x->fp16 cast + weight repack) and the edge
// binning pass.  bcur is ZERO-BASED (memset before launch).
// ---------------------------------------------------------------------------
__global__ __launch_bounds__(256) void k_preA(
    const float* __restrict__ x, __half* __restrict__ x_h,
    const float* __restrict__ W1l, const float* __restrict__ W1r,
    const float* __restrict__ W2l, const float* __restrict__ W2r,
    __half* __restrict__ W1lf, __half* __restrict__ W1rf,
    __half* __restrict__ W2f,
    const int* __restrict__ ei, int* __restrict__ bcur,
    int2* __restrict__ ebuf)
{
    __shared__ int2 scratch[TILE];   // 16 KB (binA part only)
    __shared__ int hist[NBUK];
    __shared__ int tstart[NBUK];
    __shared__ int gbase[NBUK];
    int t = threadIdx.x;

    if (blockIdx.x < PRE_BLOCKS) {
        int i = blockIdx.x * 256 + t;
        if (i < N_NODES * 32) {
            float4 v = ((const float4*)x)[i];
            __half2 a = __floats2half2_rn(v.x, v.y);
            __half2 b = __floats2half2_rn(v.z, v.w);
            uint2 u = make_uint2(*(unsigned*)&a, *(unsigned*)&b);
            ((uint2*)x_h)[i] = u;
        }
        if (i < 49152) {
            int tt = i & 16383;
            int j    = tt & 7;
            int lane = (tt >> 3) & 63;
            int ks   = (tt >> 9) & 3;
            int ct   = tt >> 11;
            int m = lane & 15, q = lane >> 4;
            int row = ct * 16 + m;
            int col = ks * 32 + q * 8 + j;
            if (i < 16384) {
                W1lf[tt] = __float2half(W1l[row * 128 + col]);
            } else if (i < 32768) {
                W1rf[tt] = __float2half(W1r[row * 128 + col]);
            } else {
                float v = (ct < 4) ? W2l[row * 128 + col]
                                   : W2r[(row - 64) * 128 + col];
                W2f[tt] = __float2half(v);
            }
        }
        return;
    }

    // ---- binA part
    int e0 = (blockIdx.x - PRE_BLOCKS) * TILE;
    int tile_n = min(TILE, N_EDGES - e0);
    if (t < NBUK) hist[t] = 0;
    __syncthreads();
    int srcs[8], dsts[8], rank[8], bks[8];
    #pragma unroll
    for (int i = 0; i < 8; ++i) {
        int e = e0 + i * 256 + t;
        bks[i] = -1;
        if (e < N_EDGES) {
            srcs[i] = ei[e];
            dsts[i] = ei[N_EDGES + e];
            bks[i]  = (dsts[i] >> BSH) & (NBUK - 1);   // guarded
            rank[i] = atomicAdd(&hist[bks[i]], 1);
        }
    }
    __syncthreads();
    if (t == 0) {
        int s = 0;
        #pragma unroll
        for (int b = 0; b < NBUK; ++b) { tstart[b] = s; s += hist[b]; }
    }
    __syncthreads();
    if (t < NBUK && hist[t] > 0)
        gbase[t] = t * CAP + atomicAdd(&bcur[t], hist[t]);
    __syncthreads();
    #pragma unroll
    for (int i = 0; i < 8; ++i)
        if (bks[i] >= 0) {
            int sl = tstart[bks[i]] + rank[i];
            scratch[min(sl, TILE - 1)] = make_int2(srcs[i], dsts[i]);
        }
    __syncthreads();
    for (int p = t; p < tile_n; p += 256) {
        int2 sd = scratch[p];
        int b = (sd.y >> BSH) & (NBUK - 1);
        int o = gbase[b] + (p - tstart[b]);
        ebuf[min(max(o, 0), NBUK * CAP - 1)] = sd;     // guarded
    }
}

// one block per bucket: inline bucket-count scan + LDS per-node histogram +
// pair-scan (row_ptr slice) + LDS-cursor fine fill.
__global__ __launch_bounds__(1024) void k_fillC2(
    const int2* __restrict__ ebuf, const int* __restrict__ bcur,
    int* __restrict__ row_ptr, int* __restrict__ csr_src)
{
    __shared__ int hist[1 << BSH];   // 8 KB
    __shared__ int psum[1024];       // 4 KB
    __shared__ int cur[1 << BSH];    // 8 KB
    __shared__ int bb_l[NBUK_USED + 1];
    int t = threadIdx.x;
    int b = blockIdx.x;
    int base = b << BSH;
    hist[t] = 0;
    hist[t + 1024] = 0;
    if (t < 64) {   // first wave: redundant exclusive scan of bucket counts
        int c = (t < NBUK_USED) ? bcur[t] : 0;
        c = min(max(c, 0), CAP);                       // guarded
        int s = c;
        #pragma unroll
        for (int off = 1; off < 64; off <<= 1) {
            int v = __shfl_up(s, off);
            if (t >= off) s += v;
        }
        if (t < NBUK_USED) bb_l[t] = s - c;
        if (t == NBUK_USED - 1) bb_l[NBUK_USED] = s;
    }
    __syncthreads();
    int bb  = bb_l[b];
    int cnt = min(bb_l[b + 1] - bb, CAP);              // guarded
    const int2* eb = ebuf + (size_t)b * CAP;
    for (int p = t; p < cnt; p += 1024)
        atomicAdd(&hist[(eb[p].y - base) & ((1 << BSH) - 1)], 1);   // guarded
    __syncthreads();
    int h0 = hist[2 * t], h1 = hist[2 * t + 1];
    psum[t] = h0 + h1;
    __syncthreads();
    #pragma unroll
    for (int off = 1; off < 1024; off <<= 1) {
        int v = (t >= off) ? psum[t - off] : 0;
        __syncthreads();
        psum[t] += v;
        __syncthreads();
    }
    int e0 = bb + psum[t] - (h0 + h1);   // exclusive over this bucket
    int e1 = e0 + h0;
    int n0g = base + 2 * t, n1g = n0g + 1;
    if (n0g <= N_NODES) row_ptr[n0g] = e0;
    if (n1g <= N_NODES) row_ptr[n1g] = e1;
    cur[2 * t]     = e0;
    cur[2 * t + 1] = e1;
    __syncthreads();
    for (int p = t; p < cnt; p += 1024) {
        int2 sd = eb[p];
        int pos = atomicAdd(&cur[(sd.y - base) & ((1 << BSH) - 1)], 1);
        csr_src[min(max(pos, 0), N_EDGES - 1)] = sd.x;  // guarded
    }
}

// ---------------------------------------------------------------------------
// K-agg1: one node per full wave, paired half-wave gathers, srcs preloaded
// via one coalesced load + readlane broadcast.  Packed fp16 accumulation,
// 8 gathers in flight.  (R16-measured: 56.8 us — fabric-bound; R14/R15
// showed both VALU-cut and MLP-double are null here.)
// ---------------------------------------------------------------------------
__device__ __forceinline__ void acc_row8h(
    const __half* __restrict__ x_h, int s, int col,
    __half2& a0, __half2& a1)
{
    uint2 u = ((const uint2*)(x_h + (size_t)(s & SMASK) * 128))[col];
    a0 = __hadd2(a0, *(__half2*)&u.x);
    a1 = __hadd2(a1, *(__half2*)&u.y);
}

__global__ __launch_bounds__(256) void k_agg1(
    const int* __restrict__ row_ptr, const int* __restrict__ csr_src,
    const __half* __restrict__ x_h, __half* __restrict__ agg_h)
{
    int tid  = threadIdx.x;
    int lane = tid & 63;
    int half = lane >> 5;     // which edge of the pair this half-wave serves
    int col  = lane & 31;     // 8-byte slice of the 256-B row
    int n    = blockIdx.x * 4 + (tid >> 6);
    int e1 = min(row_ptr[n + 1], N_EDGES);             // guarded
    int e0 = min(max(row_ptr[n], 0), e1);
    __half2 a0 = __floats2half2_rn(0.f, 0.f);
    __half2 a1 = a0;
    for (int eb = e0; eb < e1; eb += 64) {
        int cnt = min(e1 - eb, 64);
        int sv = csr_src[min(eb + lane, N_EDGES - 1)]; // guarded
        int j = 0;
        for (; j + 16 <= cnt; j += 16) {               // 8 paired gathers in flight
            int sr[8];
            #pragma unroll
            for (int u = 0; u < 8; ++u) {
                int sa = __builtin_amdgcn_readlane(sv, j + 2 * u);
                int sb = __builtin_amdgcn_readlane(sv, j + 2 * u + 1);
                sr[u] = half ? sb : sa;
            }
            #pragma unroll
            for (int u = 0; u < 8; ++u)
                acc_row8h(x_h, sr[u], col, a0, a1);
        }
        for (; j + 8 <= cnt; j += 8) {                 // 4 in flight
            int sr[4];
            #pragma unroll
            for (int u = 0; u < 4; ++u) {
                int sa = __builtin_amdgcn_readlane(sv, j + 2 * u);
                int sb = __builtin_amdgcn_readlane(sv, j + 2 * u + 1);
                sr[u] = half ? sb : sa;
            }
            #pragma unroll
            for (int u = 0; u < 4; ++u)
                acc_row8h(x_h, sr[u], col, a0, a1);
        }
        for (; j + 2 <= cnt; j += 2) {
            int sa = __builtin_amdgcn_readlane(sv, j);
            int sb = __builtin_amdgcn_readlane(sv, j + 1);
            int s  = half ? sb : sa;
            acc_row8h(x_h, s, col, a0, a1);
        }
        if (j < cnt) {
            int sa = __builtin_amdgcn_readlane(sv, j);
            if (half == 0) acc_row8h(x_h, sa, col, a0, a1);
        }
    }
    // combine the two per-edge partial sums (packed shuffle + pk_add)
    unsigned v0 = *(unsigned*)&a0, v1 = *(unsigned*)&a1;
    unsigned o0 = (unsigned)__shfl_xor((int)v0, 32);
    unsigned o1 = (unsigned)__shfl_xor((int)v1, 32);
    a0 = __hadd2(a0, *(__half2*)&o0);
    a1 = __hadd2(a1, *(__half2*)&o1);
    if (half == 0) {
        uint2 u = make_uint2(*(unsigned*)&a0, *(unsigned*)&a1);
        ((uint2*)agg_h)[n * 32 + col] = u;
    }
}

// ---------------------------------------------------------------------------
// k_g12: fused gemm1(BN/ReLU)+gemm2 with REGISTER-direct A and C.
//   Only Ah (16 KB) lives in LDS; ONE barrier per block.  (R6-measured)
// ---------------------------------------------------------------------------
__global__ __launch_bounds__(256) void k_g12(
    const __half* __restrict__ agg_h, const int* __restrict__ row_ptr,
    const __half* __restrict__ x_h,
    const __half* __restrict__ W1lf, const float* __restrict__ b1l,
    const __half* __restrict__ W1rf,
    const float* __restrict__ gamma, const float* __restrict__ beta,
    const float* __restrict__ mean, const float* __restrict__ var,
    const __half* __restrict__ W2f, const float* __restrict__ b2l,
    __half* __restrict__ p2, float* __restrict__ out)
{
    __shared__ __half Ah[16][64][8];   // 16 KB — the only LDS
    int tid  = threadIdx.x;
    int lane = tid & 63;
    int w    = tid >> 6;
    int m    = lane & 15;
    int q    = lane >> 4;
    int n0   = blockIdx.x * 64;

    int arow = n0 + w * 16 + m;
    bool aok = arow < N_NODES;
    const __half* pa = agg_h + (size_t)(aok ? arow : 0) * 128 + q * 8;
    const __half* px = x_h   + (size_t)(aok ? arow : 0) * 128 + q * 8;
    f16x8 aL[4], aR[4];
    #pragma unroll
    for (int ks = 0; ks < 4; ++ks) {
        f16x8 va = {}, vx = {};
        if (aok) {
            va = *(const f16x8*)(pa + ks * 32);
            vx = *(const f16x8*)(px + ks * 32);
        }
        aL[ks] = va;
        aR[ks] = vx;
    }
    const __half* bl0 = W1lf + (lane << 3);
    const __half* br0 = W1rf + (lane << 3);
    f32x4 accL[8], accR[8];
    #pragma unroll
    for (int c = 0; c < 8; ++c) {
        accL[c] = (f32x4){0.f, 0.f, 0.f, 0.f};
        accR[c] = (f32x4){0.f, 0.f, 0.f, 0.f};
    }
    #pragma unroll
    for (int ks = 0; ks < 4; ++ks) {
        #pragma unroll
        for (int ct = 0; ct < 8; ++ct) {
            f16x8 bL = *(const f16x8*)(bl0 + ((ct * 4 + ks) << 9));
            f16x8 bR = *(const f16x8*)(br0 + ((ct * 4 + ks) << 9));
            accL[ct] = __builtin_amdgcn_mfma_f32_16x16x32_f16(aL[ks], bL, accL[ct], 0, 0, 0);
            accR[ct] = __builtin_amdgcn_mfma_f32_16x16x32_f16(aR[ks], bR, accR[ct], 0, 0, 0);
        }
    }
    float invd[4];
    #pragma unroll
    for (int r = 0; r < 4; ++r) {
        int n = n0 + w * 16 + q * 4 + r;
        int d = (n < N_NODES) ? (row_ptr[n + 1] - row_ptr[n]) : 1;
        invd[r] = 1.0f / fmaxf((float)d, 1.0f);
    }
    #pragma unroll
    for (int ct = 0; ct < 8; ++ct) {
        int col = ct * 16 + m;
        float s = gamma[col] * rsqrtf(var[col] + 1e-5f);
        float t = beta[col] + (b1l[col] - mean[col]) * s;
        #pragma unroll
        for (int r = 0; r < 4; ++r) {
            float v = accL[ct][r] * invd[r] + accR[ct][r];
            v = fmaxf(v * s + t, 0.f);
            Ah[col >> 3][w * 16 + q * 4 + r][col & 7] = __float2half(v);
        }
    }
    __syncthreads();   // the ONLY barrier
    const __half* b0 = W2f + (lane << 3);
    f32x4 acc2[8];
    #pragma unroll
    for (int c = 0; c < 8; ++c) acc2[c] = (f32x4){0.f, 0.f, 0.f, 0.f};
    #pragma unroll
    for (int ks = 0; ks < 4; ++ks) {
        f16x8 a = *(const f16x8*)&Ah[ks * 4 + q][w * 16 + m][0];
        #pragma unroll
        for (int ct = 0; ct < 8; ++ct) {
            f16x8 b = *(const f16x8*)(b0 + ((ct * 4 + ks) << 9));
            acc2[ct] = __builtin_amdgcn_mfma_f32_16x16x32_f16(a, b, acc2[ct], 0, 0, 0);
        }
    }
    #pragma unroll
    for (int r = 0; r < 4; ++r) {
        int ng = n0 + w * 16 + q * 4 + r;
        if (ng < N_NODES) {
            #pragma unroll
            for (int ct = 0; ct < 4; ++ct)
                p2[(size_t)ng * 64 + ct * 16 + m] = __float2half(acc2[ct][r]);
            #pragma unroll
            for (int ct = 4; ct < 8; ++ct) {
                int c = (ct - 4) * 16 + m;
                out[(size_t)ng * 64 + c] = acc2[ct][r] + b2l[c];
            }
        }
    }
}

// ---------------------------------------------------------------------------
// K-agg2 (R17 rework): block-cooperative edge-parallel gather.
//   Block = 16 consecutive dst nodes; their edges are CONTIGUOUS in csr_src.
//   Each 16-lane group takes edges round-robin (uniform trip count -> zero
//   intra-wave divergence waste; old layout lost ~30-40% to E[max of 4]
//   trip-count divergence).  dst found via 4-step search over 17 LDS
//   boundaries; accumulation via f32 LDS atomicAdd (ds_add_f32) into a
//   [16][68]-padded tile (pad kills cross-group bank conflicts; in-group
//   2-way is free).  4 edges in flight per group.
// ---------------------------------------------------------------------------
__global__ __launch_bounds__(256) void k_agg2(
    const int* __restrict__ row_ptr, const int* __restrict__ csr_src,
    const __half* __restrict__ p2, float* __restrict__ out)
{
    __shared__ float acc[16][68];   // 4.25 KB (68-pad: group rows hit distinct banks)
    __shared__ int rp[17];
    int tid  = threadIdx.x;
    int n0   = blockIdx.x * 16;
    int grp  = tid >> 4;            // 16 groups of 16 lanes
    int lane = tid & 15;

    if (tid < 17) {
        int v = row_ptr[n0 + tid];
        rp[tid] = min(max(v, 0), N_EDGES);             // guarded
    }
    for (int i = tid; i < 16 * 68; i += 256)
        ((float*)acc)[i] = 0.f;
    __syncthreads();

    int e0 = rp[0], e1 = rp[16];
    // main loop: 4 edges in flight per group (stride 16 groups)
    int e = e0 + grp;
    for (; e + 48 < e1; e += 64) {
        int es[4], ss[4], rr[4];
        #pragma unroll
        for (int u = 0; u < 4; ++u) es[u] = e + u * 16;
        #pragma unroll
        for (int u = 0; u < 4; ++u) ss[u] = csr_src[es[u]];
        #pragma unroll
        for (int u = 0; u < 4; ++u) {
            int r = 0;
            #pragma unroll
            for (int step = 8; step >= 1; step >>= 1)
                if (r + step < 16 && rp[r + step] <= es[u]) r += step;
            rr[u] = r;
        }
        #pragma unroll
        for (int u = 0; u < 4; ++u) {
            uint2 v = ((const uint2*)(p2 + (size_t)(ss[u] & SMASK) * 64))[lane];
            float2 f0 = __half22float2(*(__half2*)&v.x);
            float2 f1 = __half22float2(*(__half2*)&v.y);
            float* row = &acc[rr[u]][lane * 4];
            atomicAdd(row + 0, f0.x);
            atomicAdd(row + 1, f0.y);
            atomicAdd(row + 2, f1.x);
            atomicAdd(row + 3, f1.y);
        }
    }
    for (; e < e1; e += 16) {       // tail: single edge per group
        int s = csr_src[e];
        int r = 0;
        #pragma unroll
        for (int step = 8; step >= 1; step >>= 1)
            if (r + step < 16 && rp[r + step] <= e) r += step;
        uint2 v = ((const uint2*)(p2 + (size_t)(s & SMASK) * 64))[lane];
        float2 f0 = __half22float2(*(__half2*)&v.x);
        float2 f1 = __half22float2(*(__half2*)&v.y);
        float* row = &acc[r][lane * 4];
        atomicAdd(row + 0, f0.x);
        atomicAdd(row + 1, f0.y);
        atomicAdd(row + 2, f1.x);
        atomicAdd(row + 3, f1.y);
    }
    __syncthreads();

    // epilogue: thread (rr,cc) adds acc[rr][cc*4..+4)/deg to out row n0+rr
    {
        int rrow = tid >> 4;
        int cc   = tid & 15;
        int deg  = rp[rrow + 1] - rp[rrow];
        float inv = 1.0f / fmaxf((float)deg, 1.0f);
        float4 v = *(float4*)&acc[rrow][cc * 4];
        float4* o = (float4*)(out + (size_t)(n0 + rrow) * 64) + cc;
        float4 cur = *o;
        cur.x += v.x * inv; cur.y += v.y * inv;
        cur.z += v.z * inv; cur.w += v.w * inv;
        *o = cur;
    }
}

// ---------------------------------------------------------------------------
extern "C" void kernel_launch(void* const* d_in, const int* in_sizes, int n_in,
                              void* d_out, int out_size, void* d_ws, size_t ws_size,
                              hipStream_t stream)
{
    const float* x     = (const float*)d_in[0];
    const int*   ei    = (const int*)d_in[1];
    const float* W1l   = (const float*)d_in[2];
    const float* b1l   = (const float*)d_in[3];
    const float* W1r   = (const float*)d_in[4];
    const float* gamma = (const float*)d_in[5];
    const float* beta  = (const float*)d_in[6];
    const float* mean  = (const float*)d_in[7];
    const float* var   = (const float*)d_in[8];
    const float* W2l   = (const float*)d_in[9];
    const float* b2l   = (const float*)d_in[10];
    const float* W2r   = (const float*)d_in[11];
    float* out = (float*)d_out;

    char* ws = (char*)d_ws;
    __half* agg_h   = (__half*)(ws);                  // 25.6 MB
    __half* p2      = (__half*)(ws + 25600000);       // 12.8 MB
    __half* x_h     = (__half*)(ws + 51200000);       // 25.6 MB
    int*    csr_src = (int*)(ws + 76800000);          // 6.4 MB
    int*    row_ptr = (int*)(ws + 83200000);          // 400 KB + 16
    __half* W1lf    = (__half*)(ws + 83600016);       // 32 KB
    __half* W1rf    = (__half*)(ws + 83632784);       // 32 KB
    __half* W2f     = (__half*)(ws + 83665552);       // 32 KB
    int2*   ebuf    = (int2*)(ws + 83698320);         // 18.87 MB (64*CAP*8)
    int*    bcur    = (int*)(ws + 102572688);         // 256 B

    hipMemsetAsync(bcur, 0, NBUK * sizeof(int), stream);
    k_preA<<<PRE_BLOCKS + BINA_BLOCKS, 256, 0, stream>>>(
        x, x_h, W1l, W1r, W2l, W2r, W1lf, W1rf, W2f, ei, bcur, ebuf);
    k_fillC2<<<NBUK_USED, 1024, 0, stream>>>(ebuf, bcur, row_ptr, csr_src);
    k_agg1<<<N_NODES / 4, 256, 0, stream>>>(row_ptr, csr_src, x_h, agg_h);
    k_g12<<<(N_NODES + 63) / 64, 256, 0, stream>>>(agg_h, row_ptr, x_h,
                                                   W1lf, b1l, W1rf,
                                                   gamma, beta, mean, var,
                                                   W2f, b2l, p2, out);
    k_agg2<<<N_NODES / 16, 256, 0, stream>>>(row_ptr, csr_src, p2, out);
}

// Round 18
// 307.413 us; speedup vs baseline: 2.6191x; 2.6191x over previous
//
#include <hip/hip_runtime.h>
#include <hip/hip_fp16.h>

#define N_NODES 100000
#define N_EDGES 1600000
#define TILE 2048
#define NBUK 64
#define BSH 11            // bucket = dst >> 11 (2048 nodes/bucket, 49 used)
#define NBUK_USED ((N_NODES + (1 << BSH) - 1) >> BSH)   // 49
#define CAP 36864         // fixed ebuf region per bucket
#define SMASK 0x1FFFF     // node-id guard mask (identity for id < 131072)
#define PRE_BLOCKS 12500
#define BINA_BLOCKS ((N_EDGES + TILE - 1) / TILE)       // 782

typedef _Float16 f16x8 __attribute__((ext_vector_type(8)));
typedef float    f32x4 __attribute__((ext_vector_type(4)));

// ---------------------------------------------------------------------------
// k_preA: grid-split merge of (x->fp16 cast + weight repack) and the edge
// binning pass.  bcur is ZERO-BASED (memset before launch).
// ---------------------------------------------------------------------------
__global__ __launch_bounds__(256) void k_preA(
    const float* __restrict__ x, __half* __restrict__ x_h,
    const float* __restrict__ W1l, const float* __restrict__ W1r,
    const float* __restrict__ W2l, const float* __restrict__ W2r,
    __half* __restrict__ W1lf, __half* __restrict__ W1rf,
    __half* __restrict__ W2f,
    const int* __restrict__ ei, int* __restrict__ bcur,
    int2* __restrict__ ebuf)
{
    __shared__ int2 scratch[TILE];   // 16 KB (binA part only)
    __shared__ int hist[NBUK];
    __shared__ int tstart[NBUK];
    __shared__ int gbase[NBUK];
    int t = threadIdx.x;

    if (blockIdx.x < PRE_BLOCKS) {
        int i = blockIdx.x * 256 + t;
        if (i < N_NODES * 32) {
            float4 v = ((const float4*)x)[i];
            __half2 a = __floats2half2_rn(v.x, v.y);
            __half2 b = __floats2half2_rn(v.z, v.w);
            uint2 u = make_uint2(*(unsigned*)&a, *(unsigned*)&b);
            ((uint2*)x_h)[i] = u;
        }
        if (i < 49152) {
            int tt = i & 16383;
            int j    = tt & 7;
            int lane = (tt >> 3) & 63;
            int ks   = (tt >> 9) & 3;
            int ct   = tt >> 11;
            int m = lane & 15, q = lane >> 4;
            int row = ct * 16 + m;
            int col = ks * 32 + q * 8 + j;
            if (i < 16384) {
                W1lf[tt] = __float2half(W1l[row * 128 + col]);
            } else if (i < 32768) {
                W1rf[tt] = __float2half(W1r[row * 128 + col]);
            } else {
                float v = (ct < 4) ? W2l[row * 128 + col]
                                   : W2r[(row - 64) * 128 + col];
                W2f[tt] = __float2half(v);
            }
        }
        return;
    }

    // ---- binA part
    int e0 = (blockIdx.x - PRE_BLOCKS) * TILE;
    int tile_n = min(TILE, N_EDGES - e0);
    if (t < NBUK) hist[t] = 0;
    __syncthreads();
    int srcs[8], dsts[8], rank[8], bks[8];
    #pragma unroll
    for (int i = 0; i < 8; ++i) {
        int e = e0 + i * 256 + t;
        bks[i] = -1;
        if (e < N_EDGES) {
            srcs[i] = ei[e];
            dsts[i] = ei[N_EDGES + e];
            bks[i]  = (dsts[i] >> BSH) & (NBUK - 1);   // guarded
            rank[i] = atomicAdd(&hist[bks[i]], 1);
        }
    }
    __syncthreads();
    if (t == 0) {
        int s = 0;
        #pragma unroll
        for (int b = 0; b < NBUK; ++b) { tstart[b] = s; s += hist[b]; }
    }
    __syncthreads();
    if (t < NBUK && hist[t] > 0)
        gbase[t] = t * CAP + atomicAdd(&bcur[t], hist[t]);
    __syncthreads();
    #pragma unroll
    for (int i = 0; i < 8; ++i)
        if (bks[i] >= 0) {
            int sl = tstart[bks[i]] + rank[i];
            scratch[min(sl, TILE - 1)] = make_int2(srcs[i], dsts[i]);
        }
    __syncthreads();
    for (int p = t; p < tile_n; p += 256) {
        int2 sd = scratch[p];
        int b = (sd.y >> BSH) & (NBUK - 1);
        int o = gbase[b] + (p - tstart[b]);
        ebuf[min(max(o, 0), NBUK * CAP - 1)] = sd;     // guarded
    }
}

// one block per bucket: inline bucket-count scan + LDS per-node histogram +
// pair-scan (row_ptr slice) + LDS-cursor fine fill.
__global__ __launch_bounds__(1024) void k_fillC2(
    const int2* __restrict__ ebuf, const int* __restrict__ bcur,
    int* __restrict__ row_ptr, int* __restrict__ csr_src)
{
    __shared__ int hist[1 << BSH];   // 8 KB
    __shared__ int psum[1024];       // 4 KB
    __shared__ int cur[1 << BSH];    // 8 KB
    __shared__ int bb_l[NBUK_USED + 1];
    int t = threadIdx.x;
    int b = blockIdx.x;
    int base = b << BSH;
    hist[t] = 0;
    hist[t + 1024] = 0;
    if (t < 64) {   // first wave: redundant exclusive scan of bucket counts
        int c = (t < NBUK_USED) ? bcur[t] : 0;
        c = min(max(c, 0), CAP);                       // guarded
        int s = c;
        #pragma unroll
        for (int off = 1; off < 64; off <<= 1) {
            int v = __shfl_up(s, off);
            if (t >= off) s += v;
        }
        if (t < NBUK_USED) bb_l[t] = s - c;
        if (t == NBUK_USED - 1) bb_l[NBUK_USED] = s;
    }
    __syncthreads();
    int bb  = bb_l[b];
    int cnt = min(bb_l[b + 1] - bb, CAP);              // guarded
    const int2* eb = ebuf + (size_t)b * CAP;
    for (int p = t; p < cnt; p += 1024)
        atomicAdd(&hist[(eb[p].y - base) & ((1 << BSH) - 1)], 1);   // guarded
    __syncthreads();
    int h0 = hist[2 * t], h1 = hist[2 * t + 1];
    psum[t] = h0 + h1;
    __syncthreads();
    #pragma unroll
    for (int off = 1; off < 1024; off <<= 1) {
        int v = (t >= off) ? psum[t - off] : 0;
        __syncthreads();
        psum[t] += v;
        __syncthreads();
    }
    int e0 = bb + psum[t] - (h0 + h1);   // exclusive over this bucket
    int e1 = e0 + h0;
    int n0g = base + 2 * t, n1g = n0g + 1;
    if (n0g <= N_NODES) row_ptr[n0g] = e0;
    if (n1g <= N_NODES) row_ptr[n1g] = e1;
    cur[2 * t]     = e0;
    cur[2 * t + 1] = e1;
    __syncthreads();
    for (int p = t; p < cnt; p += 1024) {
        int2 sd = eb[p];
        int pos = atomicAdd(&cur[(sd.y - base) & ((1 << BSH) - 1)], 1);
        csr_src[min(max(pos, 0), N_EDGES - 1)] = sd.x;  // guarded
    }
}

// ---------------------------------------------------------------------------
// K-agg1: one node per full wave, paired half-wave gathers, srcs preloaded
// via one coalesced load + readlane broadcast.  Packed fp16 accumulation,
// 8 gathers in flight.  (R16-measured: 56.8 us — fabric-bound; R14/R15
// showed both VALU-cut and MLP-double are null here.)
// ---------------------------------------------------------------------------
__device__ __forceinline__ void acc_row8h(
    const __half* __restrict__ x_h, int s, int col,
    __half2& a0, __half2& a1)
{
    uint2 u = ((const uint2*)(x_h + (size_t)(s & SMASK) * 128))[col];
    a0 = __hadd2(a0, *(__half2*)&u.x);
    a1 = __hadd2(a1, *(__half2*)&u.y);
}

__global__ __launch_bounds__(256) void k_agg1(
    const int* __restrict__ row_ptr, const int* __restrict__ csr_src,
    const __half* __restrict__ x_h, __half* __restrict__ agg_h)
{
    int tid  = threadIdx.x;
    int lane = tid & 63;
    int half = lane >> 5;     // which edge of the pair this half-wave serves
    int col  = lane & 31;     // 8-byte slice of the 256-B row
    int n    = blockIdx.x * 4 + (tid >> 6);
    int e1 = min(row_ptr[n + 1], N_EDGES);             // guarded
    int e0 = min(max(row_ptr[n], 0), e1);
    __half2 a0 = __floats2half2_rn(0.f, 0.f);
    __half2 a1 = a0;
    for (int eb = e0; eb < e1; eb += 64) {
        int cnt = min(e1 - eb, 64);
        int sv = csr_src[min(eb + lane, N_EDGES - 1)]; // guarded
        int j = 0;
        for (; j + 16 <= cnt; j += 16) {               // 8 paired gathers in flight
            int sr[8];
            #pragma unroll
            for (int u = 0; u < 8; ++u) {
                int sa = __builtin_amdgcn_readlane(sv, j + 2 * u);
                int sb = __builtin_amdgcn_readlane(sv, j + 2 * u + 1);
                sr[u] = half ? sb : sa;
            }
            #pragma unroll
            for (int u = 0; u < 8; ++u)
                acc_row8h(x_h, sr[u], col, a0, a1);
        }
        for (; j + 8 <= cnt; j += 8) {                 // 4 in flight
            int sr[4];
            #pragma unroll
            for (int u = 0; u < 4; ++u) {
                int sa = __builtin_amdgcn_readlane(sv, j + 2 * u);
                int sb = __builtin_amdgcn_readlane(sv, j + 2 * u + 1);
                sr[u] = half ? sb : sa;
            }
            #pragma unroll
            for (int u = 0; u < 4; ++u)
                acc_row8h(x_h, sr[u], col, a0, a1);
        }
        for (; j + 2 <= cnt; j += 2) {
            int sa = __builtin_amdgcn_readlane(sv, j);
            int sb = __builtin_amdgcn_readlane(sv, j + 1);
            int s  = half ? sb : sa;
            acc_row8h(x_h, s, col, a0, a1);
        }
        if (j < cnt) {
            int sa = __builtin_amdgcn_readlane(sv, j);
            if (half == 0) acc_row8h(x_h, sa, col, a0, a1);
        }
    }
    // combine the two per-edge partial sums (packed shuffle + pk_add)
    unsigned v0 = *(unsigned*)&a0, v1 = *(unsigned*)&a1;
    unsigned o0 = (unsigned)__shfl_xor((int)v0, 32);
    unsigned o1 = (unsigned)__shfl_xor((int)v1, 32);
    a0 = __hadd2(a0, *(__half2*)&o0);
    a1 = __hadd2(a1, *(__half2*)&o1);
    if (half == 0) {
        uint2 u = make_uint2(*(unsigned*)&a0, *(unsigned*)&a1);
        ((uint2*)agg_h)[n * 32 + col] = u;
    }
}

// ---------------------------------------------------------------------------
// k_g12: fused gemm1(BN/ReLU)+gemm2 with REGISTER-direct A and C.
//   Only Ah (16 KB) lives in LDS; ONE barrier per block.  (R6-measured)
// ---------------------------------------------------------------------------
__global__ __launch_bounds__(256) void k_g12(
    const __half* __restrict__ agg_h, const int* __restrict__ row_ptr,
    const __half* __restrict__ x_h,
    const __half* __restrict__ W1lf, const float* __restrict__ b1l,
    const __half* __restrict__ W1rf,
    const float* __restrict__ gamma, const float* __restrict__ beta,
    const float* __restrict__ mean, const float* __restrict__ var,
    const __half* __restrict__ W2f, const float* __restrict__ b2l,
    __half* __restrict__ p2, float* __restrict__ out)
{
    __shared__ __half Ah[16][64][8];   // 16 KB — the only LDS
    int tid  = threadIdx.x;
    int lane = tid & 63;
    int w    = tid >> 6;
    int m    = lane & 15;
    int q    = lane >> 4;
    int n0   = blockIdx.x * 64;

    int arow = n0 + w * 16 + m;
    bool aok = arow < N_NODES;
    const __half* pa = agg_h + (size_t)(aok ? arow : 0) * 128 + q * 8;
    const __half* px = x_h   + (size_t)(aok ? arow : 0) * 128 + q * 8;
    f16x8 aL[4], aR[4];
    #pragma unroll
    for (int ks = 0; ks < 4; ++ks) {
        f16x8 va = {}, vx = {};
        if (aok) {
            va = *(const f16x8*)(pa + ks * 32);
            vx = *(const f16x8*)(px + ks * 32);
        }
        aL[ks] = va;
        aR[ks] = vx;
    }
    const __half* bl0 = W1lf + (lane << 3);
    const __half* br0 = W1rf + (lane << 3);
    f32x4 accL[8], accR[8];
    #pragma unroll
    for (int c = 0; c < 8; ++c) {
        accL[c] = (f32x4){0.f, 0.f, 0.f, 0.f};
        accR[c] = (f32x4){0.f, 0.f, 0.f, 0.f};
    }
    #pragma unroll
    for (int ks = 0; ks < 4; ++ks) {
        #pragma unroll
        for (int ct = 0; ct < 8; ++ct) {
            f16x8 bL = *(const f16x8*)(bl0 + ((ct * 4 + ks) << 9));
            f16x8 bR = *(const f16x8*)(br0 + ((ct * 4 + ks) << 9));
            accL[ct] = __builtin_amdgcn_mfma_f32_16x16x32_f16(aL[ks], bL, accL[ct], 0, 0, 0);
            accR[ct] = __builtin_amdgcn_mfma_f32_16x16x32_f16(aR[ks], bR, accR[ct], 0, 0, 0);
        }
    }
    float invd[4];
    #pragma unroll
    for (int r = 0; r < 4; ++r) {
        int n = n0 + w * 16 + q * 4 + r;
        int d = (n < N_NODES) ? (row_ptr[n + 1] - row_ptr[n]) : 1;
        invd[r] = 1.0f / fmaxf((float)d, 1.0f);
    }
    #pragma unroll
    for (int ct = 0; ct < 8; ++ct) {
        int col = ct * 16 + m;
        float s = gamma[col] * rsqrtf(var[col] + 1e-5f);
        float t = beta[col] + (b1l[col] - mean[col]) * s;
        #pragma unroll
        for (int r = 0; r < 4; ++r) {
            float v = accL[ct][r] * invd[r] + accR[ct][r];
            v = fmaxf(v * s + t, 0.f);
            Ah[col >> 3][w * 16 + q * 4 + r][col & 7] = __float2half(v);
        }
    }
    __syncthreads();   // the ONLY barrier
    const __half* b0 = W2f + (lane << 3);
    f32x4 acc2[8];
    #pragma unroll
    for (int c = 0; c < 8; ++c) acc2[c] = (f32x4){0.f, 0.f, 0.f, 0.f};
    #pragma unroll
    for (int ks = 0; ks < 4; ++ks) {
        f16x8 a = *(const f16x8*)&Ah[ks * 4 + q][w * 16 + m][0];
        #pragma unroll
        for (int ct = 0; ct < 8; ++ct) {
            f16x8 b = *(const f16x8*)(b0 + ((ct * 4 + ks) << 9));
            acc2[ct] = __builtin_amdgcn_mfma_f32_16x16x32_f16(a, b, acc2[ct], 0, 0, 0);
        }
    }
    #pragma unroll
    for (int r = 0; r < 4; ++r) {
        int ng = n0 + w * 16 + q * 4 + r;
        if (ng < N_NODES) {
            #pragma unroll
            for (int ct = 0; ct < 4; ++ct)
                p2[(size_t)ng * 64 + ct * 16 + m] = __float2half(acc2[ct][r]);
            #pragma unroll
            for (int ct = 4; ct < 8; ++ct) {
                int c = (ct - 4) * 16 + m;
                out[(size_t)ng * 64 + c] = acc2[ct][r] + b2l[c];
            }
        }
    }
}

// ---------------------------------------------------------------------------
// K-agg2 (REVERTED to R16-measured form): 16 lanes/node, 4 nodes/wave,
// packed fp16 accumulation, 8 row-gathers in flight.
// R17's edge-parallel LDS-atomic variant was 12x slower (543 us): per-edge
// ds_add atomics serialize on the LDS atomic pipe (VALUBusy 3.4%).  Lesson:
// never put per-edge LDS atomics on the gather critical path.
// ---------------------------------------------------------------------------
__device__ __forceinline__ void acc_row_p2h(
    const __half* __restrict__ p2, int s, int lane,
    __half2& a0, __half2& a1)
{
    uint2 u = ((const uint2*)(p2 + (size_t)(s & SMASK) * 64))[lane];
    a0 = __hadd2(a0, *(__half2*)&u.x);
    a1 = __hadd2(a1, *(__half2*)&u.y);
}

__global__ __launch_bounds__(256) void k_agg2(
    const int* __restrict__ row_ptr, const int* __restrict__ csr_src,
    const __half* __restrict__ p2, float* __restrict__ out)
{
    int tid  = threadIdx.x;
    int n    = blockIdx.x * 16 + (tid >> 4);
    int lane = tid & 15;
    int e1 = min(row_ptr[n + 1], N_EDGES);             // guarded
    int e0 = min(max(row_ptr[n], 0), e1);
    __half2 a0 = __floats2half2_rn(0.f, 0.f);
    __half2 a1 = a0;
    int e = e0;
    for (; e + 8 <= e1; e += 8) {                      // 8 gathers in flight
        int s[8];
        #pragma unroll
        for (int u = 0; u < 8; ++u) s[u] = csr_src[e + u];
        #pragma unroll
        for (int u = 0; u < 8; ++u) acc_row_p2h(p2, s[u], lane, a0, a1);
    }
    for (; e + 4 <= e1; e += 4) {
        int s[4];
        #pragma unroll
        for (int u = 0; u < 4; ++u) s[u] = csr_src[e + u];
        #pragma unroll
        for (int u = 0; u < 4; ++u) acc_row_p2h(p2, s[u], lane, a0, a1);
    }
    for (; e < e1; ++e) acc_row_p2h(p2, csr_src[e], lane, a0, a1);
    float inv = 1.0f / fmaxf((float)(e1 - e0), 1.0f);
    float2 f0 = __half22float2(a0);
    float2 f1 = __half22float2(a1);
    float4* o = (float4*)out + n * 16 + lane;
    float4 cur = *o;
    cur.x += f0.x * inv; cur.y += f0.y * inv;
    cur.z += f1.x * inv; cur.w += f1.y * inv;
    *o = cur;
}

// ---------------------------------------------------------------------------
extern "C" void kernel_launch(void* const* d_in, const int* in_sizes, int n_in,
                              void* d_out, int out_size, void* d_ws, size_t ws_size,
                              hipStream_t stream)
{
    const float* x     = (const float*)d_in[0];
    const int*   ei    = (const int*)d_in[1];
    const float* W1l   = (const float*)d_in[2];
    const float* b1l   = (const float*)d_in[3];
    const float* W1r   = (const float*)d_in[4];
    const float* gamma = (const float*)d_in[5];
    const float* beta  = (const float*)d_in[6];
    const float* mean  = (const float*)d_in[7];
    const float* var   = (const float*)d_in[8];
    const float* W2l   = (const float*)d_in[9];
    const float* b2l   = (const float*)d_in[10];
    const float* W2r   = (const float*)d_in[11];
    float* out = (float*)d_out;

    char* ws = (char*)d_ws;
    __half* agg_h   = (__half*)(ws);                  // 25.6 MB
    __half* p2      = (__half*)(ws + 25600000);       // 12.8 MB
    __half* x_h     = (__half*)(ws + 51200000);       // 25.6 MB
    int*    csr_src = (int*)(ws + 76800000);          // 6.4 MB
    int*    row_ptr = (int*)(ws + 83200000);          // 400 KB + 16
    __half* W1lf    = (__half*)(ws + 83600016);       // 32 KB
    __half* W1rf    = (__half*)(ws + 83632784);       // 32 KB
    __half* W2f     = (__half*)(ws + 83665552);       // 32 KB
    int2*   ebuf    = (int2*)(ws + 83698320);         // 18.87 MB (64*CAP*8)
    int*    bcur    = (int*)(ws + 102572688);         // 256 B

    hipMemsetAsync(bcur, 0, NBUK * sizeof(int), stream);
    k_preA<<<PRE_BLOCKS + BINA_BLOCKS, 256, 0, stream>>>(
        x, x_h, W1l, W1r, W2l, W2r, W1lf, W1rf, W2f, ei, bcur, ebuf);
    k_fillC2<<<NBUK_USED, 1024, 0, stream>>>(ebuf, bcur, row_ptr, csr_src);
    k_agg1<<<N_NODES / 4, 256, 0, stream>>>(row_ptr, csr_src, x_h, agg_h);
    k_g12<<<(N_NODES + 63) / 64, 256, 0, stream>>>(agg_h, row_ptr, x_h,
                                                   W1lf, b1l, W1rf,
                                                   gamma, beta, mean, var,
                                                   W2f, b2l, p2, out);
    k_agg2<<<N_NODES / 16, 256, 0, stream>>>(row_ptr, csr_src, p2, out);
}